// Round 1
// baseline (789.300 us; speedup 1.0000x reference)
//
#include <hip/hip_runtime.h>
#include <hip/hip_bf16.h>

// Problem: B=64, T=21, E=H=512, V=10000. fp32 in/out.
// gates = x@W_ih^T + h@W_hh^T + (b_ih+b_hh); i,f,g,o order; out = h@W_lin^T + b_lin.

#define NB 64
#define NT 21
#define NE 512
#define NH 512
#define NV 10000
#define G4 2048   // 4*H

typedef __attribute__((ext_vector_type(8))) short bf16x8;  // 8 bf16 (4 VGPRs)
typedef __attribute__((ext_vector_type(4))) float f32x4;   // MFMA acc

// ---- workspace layout (bytes), all 256B-aligned ----
#define OFF_WIH_HI   0UL
#define OFF_WIH_LO   2097152UL
#define OFF_WHH_HI   4194304UL
#define OFF_WHH_LO   6291456UL
#define OFF_WLIN_HI  8388608UL     // 10,240,000 B
#define OFF_XSEQ_HI  18628608UL    // 21*64*512 bf16
#define OFF_XSEQ_LO  20004864UL
#define OFF_BIAS     21381120UL    // 2048 fp32
#define OFF_XIH      21389312UL    // 21*64*2048 fp32
#define OFF_H_HI     32399360UL    // 2 buffers x 64*512 bf16 (double-buffered across steps)
#define OFF_H_LO     32530432UL
#define OFF_C        32661504UL    // 64*512 fp32
#define OFF_HBUF     32792576UL    // 20*64*512 bf16 (h_t for phase C)
// total = 34,103,296 B

__device__ inline unsigned short f2bf(float f) {
    // round-to-nearest-even bf16
    unsigned int u = __float_as_uint(f);
    unsigned int r = u + 0x7FFFu + ((u >> 16) & 1u);
    return (unsigned short)(r >> 16);
}
__device__ inline float bf2f(unsigned short s) {
    return __uint_as_float(((unsigned int)s) << 16);
}

// ---------------- prep: bf16 hi/lo conversion + bias + X packing ----------------
// item ranges: W_ih [0,1048576), W_hh [1048576,2097152), W_lin [2097152,7217152),
// Xseq [7217152,7905280), bias [7905280,7907328)
__global__ __launch_bounds__(256) void prep_kernel(
    const float* __restrict__ features, const float* __restrict__ cap,
    const float* __restrict__ W_ih, const float* __restrict__ W_hh,
    const float* __restrict__ b_ih, const float* __restrict__ b_hh,
    const float* __restrict__ W_lin, unsigned char* __restrict__ ws)
{
    const int idx = blockIdx.x * 256 + threadIdx.x;
    unsigned short* wih_hi = (unsigned short*)(ws + OFF_WIH_HI);
    unsigned short* wih_lo = (unsigned short*)(ws + OFF_WIH_LO);
    unsigned short* whh_hi = (unsigned short*)(ws + OFF_WHH_HI);
    unsigned short* whh_lo = (unsigned short*)(ws + OFF_WHH_LO);
    unsigned short* wlin_hi = (unsigned short*)(ws + OFF_WLIN_HI);
    unsigned short* xs_hi = (unsigned short*)(ws + OFF_XSEQ_HI);
    unsigned short* xs_lo = (unsigned short*)(ws + OFF_XSEQ_LO);
    float* bias = (float*)(ws + OFF_BIAS);

    const int NW = 1048576;
    if (idx < NW) {
        float w = W_ih[idx];
        unsigned short hi = f2bf(w);
        wih_hi[idx] = hi;
        wih_lo[idx] = f2bf(w - bf2f(hi));
    } else if (idx < 2 * NW) {
        int i = idx - NW;
        float w = W_hh[i];
        unsigned short hi = f2bf(w);
        whh_hi[i] = hi;
        whh_lo[i] = f2bf(w - bf2f(hi));
    } else if (idx < 2 * NW + NV * NE) {
        int i = idx - 2 * NW;
        wlin_hi[i] = f2bf(W_lin[i]);
    } else if (idx < 2 * NW + NV * NE + NT * NB * NE) {
        int i = idx - (2 * NW + NV * NE);
        int e = i & 511;
        int b = (i >> 9) & 63;
        int t = i >> 15;  // /(64*512)
        float x = (t == 0) ? features[b * NE + e]
                           : cap[b * (NT * NE) + (t - 1) * NE + e];
        unsigned short hi = f2bf(x);
        xs_hi[i] = hi;
        xs_lo[i] = f2bf(x - bf2f(hi));
    } else if (idx < 2 * NW + NV * NE + NT * NB * NE + G4) {
        int j = idx - (2 * NW + NV * NE + NT * NB * NE);
        bias[j] = b_ih[j] + b_hh[j];
    }
}

// ---------------- phase A: Xih[1344][2048] = Xseq @ W_ih^T + bias (split bf16) ----------------
// grid (32 n-chunks, 21 m-tiles), 256 threads = 4 waves; wave = 16 rows x 64 cols
__global__ __launch_bounds__(256) void gemm_a_kernel(unsigned char* __restrict__ ws)
{
    const int lane = threadIdx.x & 63;
    const int wv = threadIdx.x >> 6;
    const int mf = lane & 15, kg = lane >> 4;
    const int n0 = blockIdx.x * 64;
    const int mBase = blockIdx.y * 64;

    const unsigned short* __restrict__ xh = (const unsigned short*)(ws + OFF_XSEQ_HI);
    const unsigned short* __restrict__ xl = (const unsigned short*)(ws + OFF_XSEQ_LO);
    const unsigned short* __restrict__ wh = (const unsigned short*)(ws + OFF_WIH_HI);
    const unsigned short* __restrict__ wl = (const unsigned short*)(ws + OFF_WIH_LO);
    const float* __restrict__ bias = (const float*)(ws + OFF_BIAS);
    float* __restrict__ xih = (float*)(ws + OFF_XIH);

    f32x4 acc[4];
#pragma unroll
    for (int q = 0; q < 4; q++) acc[q] = (f32x4){0.f, 0.f, 0.f, 0.f};

    const int arow = mBase + wv * 16 + mf;
    for (int kk = 0; kk < 512; kk += 32) {
        const int ka = kk + kg * 8;
        bf16x8 a_hi = *(const bf16x8*)(xh + arow * 512 + ka);
        bf16x8 a_lo = *(const bf16x8*)(xl + arow * 512 + ka);
#pragma unroll
        for (int ct = 0; ct < 4; ct++) {
            const int col = n0 + ct * 16 + mf;
            bf16x8 b_hi = *(const bf16x8*)(wh + col * 512 + ka);
            bf16x8 b_lo = *(const bf16x8*)(wl + col * 512 + ka);
            acc[ct] = __builtin_amdgcn_mfma_f32_16x16x32_bf16(a_hi, b_hi, acc[ct], 0, 0, 0);
            acc[ct] = __builtin_amdgcn_mfma_f32_16x16x32_bf16(a_hi, b_lo, acc[ct], 0, 0, 0);
            acc[ct] = __builtin_amdgcn_mfma_f32_16x16x32_bf16(a_lo, b_hi, acc[ct], 0, 0, 0);
        }
    }
#pragma unroll
    for (int ct = 0; ct < 4; ct++) {
        const int col = n0 + ct * 16 + mf;
        const float bb = bias[col];
#pragma unroll
        for (int r = 0; r < 4; r++) {
            const int row = mBase + wv * 16 + kg * 4 + r;
            xih[row * G4 + col] = acc[ct][r] + bb;  // row = t*64 + b
        }
    }
}

// ---------------- phase B: one LSTM step, fully fused ----------------
// grid 32 blocks (16 cols of each quadrant per block), 256 threads = 4 waves.
// h double-buffered: read buf (t+1)&1, write buf t&1.
__global__ __launch_bounds__(256) void lstm_step_kernel(unsigned char* __restrict__ ws, int t)
{
    const int lane = threadIdx.x & 63;
    const int wv = threadIdx.x >> 6;
    const int mf = lane & 15, kg = lane >> 4;
    const int bc = blockIdx.x;  // column chunk 0..31

    unsigned short* hh = (unsigned short*)(ws + OFF_H_HI);
    unsigned short* hl = (unsigned short*)(ws + OFF_H_LO);
    const int rd = (t + 1) & 1, wr = t & 1;
    const unsigned short* __restrict__ hh_r = hh + rd * (NB * NH);
    const unsigned short* __restrict__ hl_r = hl + rd * (NB * NH);
    unsigned short* __restrict__ hh_w = hh + wr * (NB * NH);
    unsigned short* __restrict__ hl_w = hl + wr * (NB * NH);
    const unsigned short* __restrict__ wh = (const unsigned short*)(ws + OFF_WHH_HI);
    const unsigned short* __restrict__ wl = (const unsigned short*)(ws + OFF_WHH_LO);
    const float* __restrict__ xih = (const float*)(ws + OFF_XIH) + (size_t)t * NB * G4;
    float* __restrict__ cbuf = (float*)(ws + OFF_C);
    unsigned short* __restrict__ hbuf = (unsigned short*)(ws + OFF_HBUF);

    f32x4 acc[4];
#pragma unroll
    for (int q = 0; q < 4; q++) acc[q] = (f32x4){0.f, 0.f, 0.f, 0.f};

    if (t > 0) {  // t==0: h=0 -> gates = Xih only
        const int arow = wv * 16 + mf;
        for (int kk = 0; kk < 512; kk += 32) {
            const int ka = kk + kg * 8;
            bf16x8 a_hi = *(const bf16x8*)(hh_r + arow * 512 + ka);
            bf16x8 a_lo = *(const bf16x8*)(hl_r + arow * 512 + ka);
#pragma unroll
            for (int q = 0; q < 4; q++) {
                const int col = q * 512 + bc * 16 + mf;
                bf16x8 b_hi = *(const bf16x8*)(wh + col * 512 + ka);
                bf16x8 b_lo = *(const bf16x8*)(wl + col * 512 + ka);
                acc[q] = __builtin_amdgcn_mfma_f32_16x16x32_bf16(a_hi, b_hi, acc[q], 0, 0, 0);
                acc[q] = __builtin_amdgcn_mfma_f32_16x16x32_bf16(a_hi, b_lo, acc[q], 0, 0, 0);
                acc[q] = __builtin_amdgcn_mfma_f32_16x16x32_bf16(a_lo, b_hi, acc[q], 0, 0, 0);
            }
        }
    }

    // epilogue: lane holds i,f,g,o at identical (m,c) positions -> in-register LSTM cell
    const int c = bc * 16 + mf;
#pragma unroll
    for (int r = 0; r < 4; r++) {
        const int m = wv * 16 + kg * 4 + r;
        const float gi = acc[0][r] + xih[m * G4 + 0 * 512 + c];
        const float gf = acc[1][r] + xih[m * G4 + 1 * 512 + c];
        const float gg = acc[2][r] + xih[m * G4 + 2 * 512 + c];
        const float go = acc[3][r] + xih[m * G4 + 3 * 512 + c];
        const float i_ = 1.f / (1.f + __expf(-gi));
        const float f_ = 1.f / (1.f + __expf(-gf));
        const float g_ = tanhf(gg);
        const float o_ = 1.f / (1.f + __expf(-go));
        const float c_old = (t == 0) ? 0.f : cbuf[m * NH + c];
        const float c_new = f_ * c_old + i_ * g_;
        cbuf[m * NH + c] = c_new;
        const float h_new = o_ * tanhf(c_new);
        const unsigned short hi = f2bf(h_new);
        hh_w[m * NH + c] = hi;
        hl_w[m * NH + c] = f2bf(h_new - bf2f(hi));
        if (t >= 1) hbuf[(t - 1) * (NB * NH) + m * NH + c] = hi;
    }
}

// ---------------- phase C: Out[b][t][v] = Hbuf @ W_lin^T + b_lin (bf16) ----------------
// grid (157 n-chunks of 64, 20 t), 256 threads = 4 waves; wave = 16 rows x 64 cols
__global__ __launch_bounds__(256) void gemm_c_kernel(
    unsigned char* __restrict__ ws, const float* __restrict__ b_lin, float* __restrict__ out)
{
    const int lane = threadIdx.x & 63;
    const int wv = threadIdx.x >> 6;
    const int mf = lane & 15, kg = lane >> 4;
    const int n0 = blockIdx.x * 64;
    const int tt = blockIdx.y;

    const unsigned short* __restrict__ hb =
        (const unsigned short*)(ws + OFF_HBUF) + (size_t)tt * (NB * NH);
    const unsigned short* __restrict__ wlin = (const unsigned short*)(ws + OFF_WLIN_HI);

    f32x4 acc[4];
    bool valid[4];
#pragma unroll
    for (int ct = 0; ct < 4; ct++) {
        acc[ct] = (f32x4){0.f, 0.f, 0.f, 0.f};
        valid[ct] = (n0 + ct * 16) < NV;  // NV % 16 == 0 -> tile fully valid or fully out
    }

    const int arow = wv * 16 + mf;  // batch index
    for (int kk = 0; kk < 512; kk += 32) {
        const int ka = kk + kg * 8;
        bf16x8 a = *(const bf16x8*)(hb + arow * 512 + ka);
#pragma unroll
        for (int ct = 0; ct < 4; ct++) {
            if (valid[ct]) {
                const int col = n0 + ct * 16 + mf;
                bf16x8 b = *(const bf16x8*)(wlin + col * 512 + ka);
                acc[ct] = __builtin_amdgcn_mfma_f32_16x16x32_bf16(a, b, acc[ct], 0, 0, 0);
            }
        }
    }
#pragma unroll
    for (int ct = 0; ct < 4; ct++) {
        if (!valid[ct]) continue;
        const int col = n0 + ct * 16 + mf;
        const float bl = b_lin[col];
#pragma unroll
        for (int r = 0; r < 4; r++) {
            const int b_ = wv * 16 + kg * 4 + r;
            out[(size_t)b_ * ((NT - 1) * NV) + (size_t)tt * NV + col] = acc[ct][r] + bl;
        }
    }
}

extern "C" void kernel_launch(void* const* d_in, const int* in_sizes, int n_in,
                              void* d_out, int out_size, void* d_ws, size_t ws_size,
                              hipStream_t stream)
{
    const float* features = (const float*)d_in[0];
    const float* cap      = (const float*)d_in[1];
    const float* W_ih     = (const float*)d_in[2];
    const float* W_hh     = (const float*)d_in[3];
    const float* b_ih     = (const float*)d_in[4];
    const float* b_hh     = (const float*)d_in[5];
    const float* W_lin    = (const float*)d_in[6];
    const float* b_lin    = (const float*)d_in[7];
    float* out = (float*)d_out;
    unsigned char* ws = (unsigned char*)d_ws;

    // prep: 7,907,328 items / 256 = 30888 blocks exactly
    hipLaunchKernelGGL(prep_kernel, dim3(30888), dim3(256), 0, stream,
                       features, cap, W_ih, W_hh, b_ih, b_hh, W_lin, ws);
    // phase A: all input projections
    hipLaunchKernelGGL(gemm_a_kernel, dim3(32, 21), dim3(256), 0, stream, ws);
    // phase B: 21 sequential fused LSTM steps
    for (int t = 0; t < NT; t++) {
        hipLaunchKernelGGL(lstm_step_kernel, dim3(32), dim3(256), 0, stream, ws, t);
    }
    // phase C: output projection
    hipLaunchKernelGGL(gemm_c_kernel, dim3(157, 20), dim3(256), 0, stream, ws, b_lin, out);
}

// Round 2
// 586.443 us; speedup vs baseline: 1.3459x; 1.3459x over previous
//
#include <hip/hip_runtime.h>
#include <hip/hip_bf16.h>

// B=64, T=21, E=H=512, V=10000. fp32 in/out.
// gates = x@W_ih^T + h@W_hh^T + (b_ih+b_hh); i,f,g,o; out = h@W_lin^T + b_lin.

#define NB 64
#define NT 21
#define NE 512
#define NH 512
#define NV 10000
#define NVP 10112   // padded to 79*128
#define G4 2048
#define MPA 1408    // padded Xseq rows (21*64=1344 -> 11*128)

typedef __attribute__((ext_vector_type(8))) short bf16x8;
typedef __attribute__((ext_vector_type(4))) float f32x4;

// ---- workspace layout (bytes) ----
#define OFF_WIH_HI   0UL
#define OFF_WIH_LO   2097152UL
#define OFF_WHH_HI   4194304UL
#define OFF_WHH_LO   6291456UL
#define OFF_WLIN_HI  8388608UL     // 10112*512*2 = 10,354,688
#define OFF_XSEQ_HI  18743296UL    // 1408*512*2 = 1,441,792
#define OFF_XSEQ_LO  20185088UL
#define OFF_BIAS     21626880UL    // 2048*4
#define OFF_XIH      21635072UL    // 21*64*2048*4 = 11,010,048
#define OFF_H_HI     32645120UL    // 2 x 64*512 bf16
#define OFF_H_LO     32776192UL
#define OFF_C        32907264UL    // 64*512 f32
#define OFF_HBUF     33038336UL    // 20*64*512 bf16
#define OFF_BAR      34349056UL    // barrier counters
// total ~34.35 MB

__device__ inline unsigned short f2bf(float f) {
    unsigned int u = __float_as_uint(f);
    unsigned int r = u + 0x7FFFu + ((u >> 16) & 1u);
    return (unsigned short)(r >> 16);
}
__device__ inline float bf2f(unsigned short s) {
    return __uint_as_float(((unsigned int)s) << 16);
}

// async global->LDS, 16B per lane (CK-style addrspace casts)
__device__ __forceinline__ void gl_lds16(const unsigned short* g, unsigned short* l) {
    auto gp = (const __attribute__((address_space(1))) unsigned int*)(unsigned long long)(const void*)g;
    auto lp = (__attribute__((address_space(3))) unsigned int*)(unsigned int)(unsigned long long)(void*)l;
    __builtin_amdgcn_global_load_lds(gp, lp, 16, 0, 0);
}

// ---------------- prep ----------------
__global__ __launch_bounds__(256) void prep_kernel(
    const float* __restrict__ features, const float* __restrict__ cap,
    const float* __restrict__ W_ih, const float* __restrict__ W_hh,
    const float* __restrict__ b_ih, const float* __restrict__ b_hh,
    const float* __restrict__ W_lin, unsigned char* __restrict__ ws)
{
    const int idx = blockIdx.x * 256 + threadIdx.x;
    unsigned short* wih_hi = (unsigned short*)(ws + OFF_WIH_HI);
    unsigned short* wih_lo = (unsigned short*)(ws + OFF_WIH_LO);
    unsigned short* whh_hi = (unsigned short*)(ws + OFF_WHH_HI);
    unsigned short* whh_lo = (unsigned short*)(ws + OFF_WHH_LO);
    unsigned short* wlin_hi = (unsigned short*)(ws + OFF_WLIN_HI);
    unsigned short* xs_hi = (unsigned short*)(ws + OFF_XSEQ_HI);
    unsigned short* xs_lo = (unsigned short*)(ws + OFF_XSEQ_LO);
    float* bias = (float*)(ws + OFF_BIAS);

    const int NW = 1048576;
    if (idx < NW) {
        float w = W_ih[idx];
        unsigned short hi = f2bf(w);
        wih_hi[idx] = hi;
        wih_lo[idx] = f2bf(w - bf2f(hi));
    } else if (idx < 2 * NW) {
        int i = idx - NW;
        float w = W_hh[i];
        unsigned short hi = f2bf(w);
        whh_hi[i] = hi;
        whh_lo[i] = f2bf(w - bf2f(hi));
    } else if (idx < 2 * NW + NV * NE) {
        int i = idx - 2 * NW;
        wlin_hi[i] = f2bf(W_lin[i]);
    } else if (idx < 2 * NW + NV * NE + NT * NB * NE) {
        int i = idx - (2 * NW + NV * NE);
        int e = i & 511;
        int b = (i >> 9) & 63;
        int t = i >> 15;
        float x = (t == 0) ? features[b * NE + e]
                           : cap[b * (NT * NE) + (t - 1) * NE + e];
        unsigned short hi = f2bf(x);
        xs_hi[i] = hi;
        xs_lo[i] = f2bf(x - bf2f(hi));
    } else if (idx < 2 * NW + NV * NE + NT * NB * NE + G4) {
        int j = idx - (2 * NW + NV * NE + NT * NB * NE);
        bias[j] = b_ih[j] + b_hh[j];
    }
}

// ---------------- phase A: Xih = Xseq @ W_ih^T + bias, hi/lo 3-pass, tiled ----------------
// grid (16 n-tiles, 11 m-tiles), 256 thr = 4 waves, tile 128x128, BK=32
__global__ __launch_bounds__(256) void gemm_a_kernel(unsigned char* __restrict__ ws)
{
    __shared__ unsigned short Ah[2][4096], Al[2][4096], Bh[2][4096], Bl[2][4096];
    const int tid = threadIdx.x;
    const int lane = tid & 63, wv = tid >> 6;
    const int mf = lane & 15, kg = lane >> 4;
    const int mw = (wv >> 1) * 64, nw = (wv & 1) * 64;
    const int m0 = blockIdx.y * 128, n0 = blockIdx.x * 128;

    const unsigned short* __restrict__ xh = (const unsigned short*)(ws + OFF_XSEQ_HI);
    const unsigned short* __restrict__ xl = (const unsigned short*)(ws + OFF_XSEQ_LO);
    const unsigned short* __restrict__ wh = (const unsigned short*)(ws + OFF_WIH_HI);
    const unsigned short* __restrict__ wl = (const unsigned short*)(ws + OFF_WIH_LO);
    const float* __restrict__ bias = (const float*)(ws + OFF_BIAS);
    float* __restrict__ xih = (float*)(ws + OFF_XIH);

    f32x4 acc[4][4];
#pragma unroll
    for (int i = 0; i < 4; i++)
#pragma unroll
        for (int j = 0; j < 4; j++) acc[i][j] = (f32x4){0.f, 0.f, 0.f, 0.f};

    auto stage = [&](int buf, int k0) {
#pragma unroll
        for (int h = 0; h < 2; ++h) {
            int s = h * 256 + tid;
            int r = s >> 2, ks = (s & 3) * 8;
            gl_lds16(xh + (size_t)(m0 + r) * 512 + k0 + ks, &Ah[buf][s * 8]);
            gl_lds16(xl + (size_t)(m0 + r) * 512 + k0 + ks, &Al[buf][s * 8]);
            gl_lds16(wh + (size_t)(n0 + r) * 512 + k0 + ks, &Bh[buf][s * 8]);
            gl_lds16(wl + (size_t)(n0 + r) * 512 + k0 + ks, &Bl[buf][s * 8]);
        }
    };

    stage(0, 0);
    for (int kt = 0; kt < 16; ++kt) {
        __syncthreads();
        const int cur = kt & 1;
        if (kt < 15) stage(cur ^ 1, (kt + 1) * 32);
        bf16x8 ah[4], al[4], bh[4], bl[4];
#pragma unroll
        for (int i = 0; i < 4; i++) {
            ah[i] = *(const bf16x8*)&Ah[cur][(mw + i * 16 + mf) * 32 + kg * 8];
            al[i] = *(const bf16x8*)&Al[cur][(mw + i * 16 + mf) * 32 + kg * 8];
            bh[i] = *(const bf16x8*)&Bh[cur][(nw + i * 16 + mf) * 32 + kg * 8];
            bl[i] = *(const bf16x8*)&Bl[cur][(nw + i * 16 + mf) * 32 + kg * 8];
        }
#pragma unroll
        for (int i = 0; i < 4; i++)
#pragma unroll
            for (int j = 0; j < 4; j++) {
                acc[i][j] = __builtin_amdgcn_mfma_f32_16x16x32_bf16(ah[i], bh[j], acc[i][j], 0, 0, 0);
                acc[i][j] = __builtin_amdgcn_mfma_f32_16x16x32_bf16(ah[i], bl[j], acc[i][j], 0, 0, 0);
                acc[i][j] = __builtin_amdgcn_mfma_f32_16x16x32_bf16(al[i], bh[j], acc[i][j], 0, 0, 0);
            }
    }
#pragma unroll
    for (int i = 0; i < 4; i++)
#pragma unroll
        for (int j = 0; j < 4; j++) {
            const int col = n0 + nw + j * 16 + mf;
            const float bb = bias[col];
#pragma unroll
            for (int r = 0; r < 4; r++) {
                const int R = m0 + mw + i * 16 + kg * 4 + r;
                if (R < NT * NB) xih[(size_t)R * G4 + col] = acc[i][j][r] + bb;
            }
        }
}

// ---------------- phase B: persistent LSTM, 32 blocks, grid barrier per step ----------------
__global__ __launch_bounds__(256) void lstm_persistent(unsigned char* __restrict__ ws)
{
    __shared__ unsigned short Bhi[64 * 512];  // 64 KB, XOR-swizzled 16B chunks
    const int tid = threadIdx.x;
    const int lane = tid & 63, wv = tid >> 6;
    const int mf = lane & 15, kg = lane >> 4;
    const int bc = blockIdx.x;  // 0..31, owns cols bc*16..+15 of each quadrant

    unsigned short* hh = (unsigned short*)(ws + OFF_H_HI);
    unsigned short* hl = (unsigned short*)(ws + OFF_H_LO);
    const unsigned short* __restrict__ whh_hi = (const unsigned short*)(ws + OFF_WHH_HI);
    const unsigned short* __restrict__ whh_lo = (const unsigned short*)(ws + OFF_WHH_LO);
    const float* __restrict__ xih_base = (const float*)(ws + OFF_XIH);
    float* __restrict__ cbuf = (float*)(ws + OFF_C);
    unsigned short* __restrict__ hbuf = (unsigned short*)(ws + OFF_HBUF);
    unsigned int* __restrict__ bars = (unsigned int*)(ws + OFF_BAR);

    // Stage W_hh-hi for our 64 eq-cols once. chunk swizzle: cidx = e*64 + (j ^ (e&7))
    for (int h = 0; h < 16; ++h) {
        int s = h * 256 + tid;            // 0..4095
        int e = s >> 6, j = s & 63;
        int q = e >> 4, ci = e & 15;
        const unsigned short* g = whh_hi + ((size_t)(q * 512 + bc * 16 + ci) * 512 + j * 8);
        bf16x8 v = *(const bf16x8*)g;
        *(bf16x8*)&Bhi[(e * 64 + (j ^ (e & 7))) * 8] = v;
    }
    __syncthreads();

    for (int t = 0; t < NT; ++t) {
        f32x4 acc[4];
#pragma unroll
        for (int q = 0; q < 4; q++) acc[q] = (f32x4){0.f, 0.f, 0.f, 0.f};

        if (t > 0) {
            const int rd = (t + 1) & 1;
            const unsigned short* __restrict__ hh_r = hh + rd * (NB * NH);
            const unsigned short* __restrict__ hl_r = hl + rd * (NB * NH);
            const int arow = wv * 16 + mf;
            for (int kk = 0; kk < 512; kk += 32) {
                const int ka = kk + kg * 8;
                const int jj = (kk >> 3) + kg;
                bf16x8 a_hi = *(const bf16x8*)(hh_r + arow * 512 + ka);
                bf16x8 a_lo = *(const bf16x8*)(hl_r + arow * 512 + ka);
#pragma unroll
                for (int q = 0; q < 4; q++) {
                    const int e = q * 16 + mf;
                    bf16x8 b_hi = *(const bf16x8*)&Bhi[(e * 64 + (jj ^ (e & 7))) * 8];
                    bf16x8 b_lo = *(const bf16x8*)(whh_lo + (size_t)(q * 512 + bc * 16 + mf) * 512 + ka);
                    acc[q] = __builtin_amdgcn_mfma_f32_16x16x32_bf16(a_hi, b_hi, acc[q], 0, 0, 0);
                    acc[q] = __builtin_amdgcn_mfma_f32_16x16x32_bf16(a_hi, b_lo, acc[q], 0, 0, 0);
                    acc[q] = __builtin_amdgcn_mfma_f32_16x16x32_bf16(a_lo, b_hi, acc[q], 0, 0, 0);
                }
            }
        }

        const int wr = t & 1;
        unsigned short* __restrict__ hh_w = hh + wr * (NB * NH);
        unsigned short* __restrict__ hl_w = hl + wr * (NB * NH);
        const float* __restrict__ xih = xih_base + (size_t)t * NB * G4;
        const int c = bc * 16 + mf;
#pragma unroll
        for (int r = 0; r < 4; r++) {
            const int m = wv * 16 + kg * 4 + r;
            const float gi = acc[0][r] + xih[m * G4 + 0 * 512 + c];
            const float gf = acc[1][r] + xih[m * G4 + 1 * 512 + c];
            const float gg = acc[2][r] + xih[m * G4 + 2 * 512 + c];
            const float go = acc[3][r] + xih[m * G4 + 3 * 512 + c];
            const float i_ = 1.f / (1.f + __expf(-gi));
            const float f_ = 1.f / (1.f + __expf(-gf));
            const float g_ = tanhf(gg);
            const float o_ = 1.f / (1.f + __expf(-go));
            const float c_old = (t == 0) ? 0.f : cbuf[m * NH + c];
            const float c_new = f_ * c_old + i_ * g_;
            cbuf[m * NH + c] = c_new;
            const float h_new = o_ * tanhf(c_new);
            const unsigned short hi = f2bf(h_new);
            hh_w[m * NH + c] = hi;
            hl_w[m * NH + c] = f2bf(h_new - bf2f(hi));
            if (t >= 1) hbuf[(t - 1) * (NB * NH) + m * NH + c] = hi;
        }

        if (t < NT - 1) {
            __threadfence();
            __syncthreads();
            if (tid == 0) {
                atomicAdd(&bars[t], 1u);
                while (__hip_atomic_load(&bars[t], __ATOMIC_ACQUIRE, __HIP_MEMORY_SCOPE_AGENT)
                       < (unsigned)gridDim.x) {
                    __builtin_amdgcn_s_sleep(1);
                }
            }
            __syncthreads();
            __builtin_amdgcn_fence(__ATOMIC_ACQUIRE, "agent");
        }
    }
}

// ---------------- phase C: Out = Hbuf[1280x512] @ W_lin^T + b_lin, tiled ----------------
// grid (79 n-tiles, 10 m-tiles), 256 thr = 4 waves, tile 128x128, BK=32
__global__ __launch_bounds__(256) void gemm_c_kernel(
    unsigned char* __restrict__ ws, const float* __restrict__ b_lin, float* __restrict__ out)
{
    __shared__ unsigned short As[2][4096], Bs[2][4096];
    const int tid = threadIdx.x;
    const int lane = tid & 63, wv = tid >> 6;
    const int mf = lane & 15, kg = lane >> 4;
    const int mw = (wv >> 1) * 64, nw = (wv & 1) * 64;
    const int m0 = blockIdx.y * 128, n0 = blockIdx.x * 128;

    const unsigned short* __restrict__ hb = (const unsigned short*)(ws + OFF_HBUF);
    const unsigned short* __restrict__ wlin = (const unsigned short*)(ws + OFF_WLIN_HI);

    f32x4 acc[4][4];
#pragma unroll
    for (int i = 0; i < 4; i++)
#pragma unroll
        for (int j = 0; j < 4; j++) acc[i][j] = (f32x4){0.f, 0.f, 0.f, 0.f};

    auto stage = [&](int buf, int k0) {
#pragma unroll
        for (int h = 0; h < 2; ++h) {
            int s = h * 256 + tid;
            int r = s >> 2, ks = (s & 3) * 8;
            gl_lds16(hb + (size_t)(m0 + r) * 512 + k0 + ks, &As[buf][s * 8]);
            gl_lds16(wlin + (size_t)(n0 + r) * 512 + k0 + ks, &Bs[buf][s * 8]);
        }
    };

    stage(0, 0);
    for (int kt = 0; kt < 16; ++kt) {
        __syncthreads();
        const int cur = kt & 1;
        if (kt < 15) stage(cur ^ 1, (kt + 1) * 32);
        bf16x8 af[4], bf[4];
#pragma unroll
        for (int i = 0; i < 4; i++) {
            af[i] = *(const bf16x8*)&As[cur][(mw + i * 16 + mf) * 32 + kg * 8];
            bf[i] = *(const bf16x8*)&Bs[cur][(nw + i * 16 + mf) * 32 + kg * 8];
        }
#pragma unroll
        for (int i = 0; i < 4; i++)
#pragma unroll
            for (int j = 0; j < 4; j++)
                acc[i][j] = __builtin_amdgcn_mfma_f32_16x16x32_bf16(af[i], bf[j], acc[i][j], 0, 0, 0);
    }
#pragma unroll
    for (int i = 0; i < 4; i++)
#pragma unroll
        for (int j = 0; j < 4; j++) {
            const int col = n0 + nw + j * 16 + mf;
            if (col < NV) {
                const float bl = b_lin[col];
#pragma unroll
                for (int r = 0; r < 4; r++) {
                    const int R = m0 + mw + i * 16 + kg * 4 + r;  // = t*64 + b
                    const int b_ = R & 63, tt = R >> 6;
                    out[(size_t)b_ * ((NT - 1) * NV) + (size_t)tt * NV + col] = acc[i][j][r] + bl;
                }
            }
        }
}

extern "C" void kernel_launch(void* const* d_in, const int* in_sizes, int n_in,
                              void* d_out, int out_size, void* d_ws, size_t ws_size,
                              hipStream_t stream)
{
    const float* features = (const float*)d_in[0];
    const float* cap      = (const float*)d_in[1];
    const float* W_ih     = (const float*)d_in[2];
    const float* W_hh     = (const float*)d_in[3];
    const float* b_ih     = (const float*)d_in[4];
    const float* b_hh     = (const float*)d_in[5];
    const float* W_lin    = (const float*)d_in[6];
    const float* b_lin    = (const float*)d_in[7];
    float* out = (float*)d_out;
    unsigned char* ws = (unsigned char*)d_ws;

    // zero the grid-barrier counters (ws is poisoned 0xAA before every launch)
    hipMemsetAsync(ws + OFF_BAR, 0, 64 * sizeof(unsigned int), stream);

    hipLaunchKernelGGL(prep_kernel, dim3(30888), dim3(256), 0, stream,
                       features, cap, W_ih, W_hh, b_ih, b_hh, W_lin, ws);
    hipLaunchKernelGGL(gemm_a_kernel, dim3(16, 11), dim3(256), 0, stream, ws);
    hipLaunchKernelGGL(lstm_persistent, dim3(32), dim3(256), 0, stream, ws);
    hipLaunchKernelGGL(gemm_c_kernel, dim3(79, 10), dim3(256), 0, stream, ws, b_lin, out);
}

// Round 3
// 560.562 us; speedup vs baseline: 1.4081x; 1.0462x over previous
//
#include <hip/hip_runtime.h>
#include <hip/hip_bf16.h>

// B=64, T=21, E=H=512, V=10000. fp32 in/out.
// gates = x@W_ih^T + h@W_hh^T + (b_ih+b_hh); i,f,g,o; out = h@W_lin^T + b_lin.

#define NB 64
#define NT 21
#define NE 512
#define NH 512
#define NV 10000
#define NVP 10112   // padded to 79*128
#define G4 2048
#define MPA 1408    // padded Xseq rows (21*64=1344 -> 11*128)

typedef __attribute__((ext_vector_type(8))) short bf16x8;
typedef __attribute__((ext_vector_type(4))) float f32x4;

// ---- workspace layout (bytes) ----
#define OFF_WIH_HI   0UL
#define OFF_WIH_LO   2097152UL
#define OFF_WHH_HI   4194304UL
#define OFF_WHH_LO   6291456UL
#define OFF_WLIN_HI  8388608UL     // 10112*512*2 = 10,354,688
#define OFF_XSEQ_HI  18743296UL    // 1408*512*2
#define OFF_XSEQ_LO  20185088UL
#define OFF_BIAS     21626880UL    // 2048*4
#define OFF_XIH      21635072UL    // 21*64*2048*4
#define OFF_HPK      32645120UL    // 2 x 64*512 u32 (packed hi<<16|lo), 256KB
#define OFF_C        32907264UL    // 64*512 f32
#define OFF_HBUF     33038336UL    // 20*64*512 bf16
#define OFF_FLG      34349056UL    // 20*32 u32 barrier flags
// end 34,351,616 B

__device__ inline unsigned short f2bf(float f) {
    unsigned int u = __float_as_uint(f);
    unsigned int r = u + 0x7FFFu + ((u >> 16) & 1u);
    return (unsigned short)(r >> 16);
}
__device__ inline float bf2f(unsigned short s) {
    return __uint_as_float(((unsigned int)s) << 16);
}

__device__ __forceinline__ void gl_lds16(const unsigned short* g, unsigned short* l) {
    auto gp = (const __attribute__((address_space(1))) unsigned int*)(unsigned long long)(const void*)g;
    auto lp = (__attribute__((address_space(3))) unsigned int*)(unsigned int)(unsigned long long)(void*)l;
    __builtin_amdgcn_global_load_lds(gp, lp, 16, 0, 0);
}

// ---------------- prep ----------------
__global__ __launch_bounds__(256) void prep_kernel(
    const float* __restrict__ features, const float* __restrict__ cap,
    const float* __restrict__ W_ih, const float* __restrict__ W_hh,
    const float* __restrict__ b_ih, const float* __restrict__ b_hh,
    const float* __restrict__ W_lin, unsigned char* __restrict__ ws)
{
    const int idx = blockIdx.x * 256 + threadIdx.x;
    unsigned short* wih_hi = (unsigned short*)(ws + OFF_WIH_HI);
    unsigned short* wih_lo = (unsigned short*)(ws + OFF_WIH_LO);
    unsigned short* whh_hi = (unsigned short*)(ws + OFF_WHH_HI);
    unsigned short* whh_lo = (unsigned short*)(ws + OFF_WHH_LO);
    unsigned short* wlin_hi = (unsigned short*)(ws + OFF_WLIN_HI);
    unsigned short* xs_hi = (unsigned short*)(ws + OFF_XSEQ_HI);
    unsigned short* xs_lo = (unsigned short*)(ws + OFF_XSEQ_LO);
    float* bias = (float*)(ws + OFF_BIAS);

    const int NW = 1048576;
    if (idx < NW) {
        float w = W_ih[idx];
        unsigned short hi = f2bf(w);
        wih_hi[idx] = hi;
        wih_lo[idx] = f2bf(w - bf2f(hi));
    } else if (idx < 2 * NW) {
        int i = idx - NW;
        float w = W_hh[i];
        unsigned short hi = f2bf(w);
        whh_hi[i] = hi;
        whh_lo[i] = f2bf(w - bf2f(hi));
    } else if (idx < 2 * NW + NV * NE) {
        int i = idx - 2 * NW;
        wlin_hi[i] = f2bf(W_lin[i]);
    } else if (idx < 2 * NW + NV * NE + NT * NB * NE) {
        int i = idx - (2 * NW + NV * NE);
        int e = i & 511;
        int b = (i >> 9) & 63;
        int t = i >> 15;
        float x = (t == 0) ? features[b * NE + e]
                           : cap[b * (NT * NE) + (t - 1) * NE + e];
        unsigned short hi = f2bf(x);
        xs_hi[i] = hi;
        xs_lo[i] = f2bf(x - bf2f(hi));
    } else if (idx < 2 * NW + NV * NE + NT * NB * NE + G4) {
        int j = idx - (2 * NW + NV * NE + NT * NB * NE);
        bias[j] = b_ih[j] + b_hh[j];
    }
}

// ---------------- phase A: Xih = Xseq @ W_ih^T + bias, hi/lo 3-pass, tiled ----------------
__global__ __launch_bounds__(256) void gemm_a_kernel(unsigned char* __restrict__ ws)
{
    __shared__ unsigned short Ah[2][4096], Al[2][4096], Bh[2][4096], Bl[2][4096];
    const int tid = threadIdx.x;
    const int lane = tid & 63, wv = tid >> 6;
    const int mf = lane & 15, kg = lane >> 4;
    const int mw = (wv >> 1) * 64, nw = (wv & 1) * 64;
    const int m0 = blockIdx.y * 128, n0 = blockIdx.x * 128;

    const unsigned short* __restrict__ xh = (const unsigned short*)(ws + OFF_XSEQ_HI);
    const unsigned short* __restrict__ xl = (const unsigned short*)(ws + OFF_XSEQ_LO);
    const unsigned short* __restrict__ wh = (const unsigned short*)(ws + OFF_WIH_HI);
    const unsigned short* __restrict__ wl = (const unsigned short*)(ws + OFF_WIH_LO);
    const float* __restrict__ bias = (const float*)(ws + OFF_BIAS);
    float* __restrict__ xih = (float*)(ws + OFF_XIH);

    f32x4 acc[4][4];
#pragma unroll
    for (int i = 0; i < 4; i++)
#pragma unroll
        for (int j = 0; j < 4; j++) acc[i][j] = (f32x4){0.f, 0.f, 0.f, 0.f};

    auto stage = [&](int buf, int k0) {
#pragma unroll
        for (int h = 0; h < 2; ++h) {
            int s = h * 256 + tid;
            int r = s >> 2, ks = (s & 3) * 8;
            gl_lds16(xh + (size_t)(m0 + r) * 512 + k0 + ks, &Ah[buf][s * 8]);
            gl_lds16(xl + (size_t)(m0 + r) * 512 + k0 + ks, &Al[buf][s * 8]);
            gl_lds16(wh + (size_t)(n0 + r) * 512 + k0 + ks, &Bh[buf][s * 8]);
            gl_lds16(wl + (size_t)(n0 + r) * 512 + k0 + ks, &Bl[buf][s * 8]);
        }
    };

    stage(0, 0);
    for (int kt = 0; kt < 16; ++kt) {
        __syncthreads();
        const int cur = kt & 1;
        if (kt < 15) stage(cur ^ 1, (kt + 1) * 32);
        bf16x8 ah[4], al[4], bh[4], bl[4];
#pragma unroll
        for (int i = 0; i < 4; i++) {
            ah[i] = *(const bf16x8*)&Ah[cur][(mw + i * 16 + mf) * 32 + kg * 8];
            al[i] = *(const bf16x8*)&Al[cur][(mw + i * 16 + mf) * 32 + kg * 8];
            bh[i] = *(const bf16x8*)&Bh[cur][(nw + i * 16 + mf) * 32 + kg * 8];
            bl[i] = *(const bf16x8*)&Bl[cur][(nw + i * 16 + mf) * 32 + kg * 8];
        }
#pragma unroll
        for (int i = 0; i < 4; i++)
#pragma unroll
            for (int j = 0; j < 4; j++) {
                acc[i][j] = __builtin_amdgcn_mfma_f32_16x16x32_bf16(ah[i], bh[j], acc[i][j], 0, 0, 0);
                acc[i][j] = __builtin_amdgcn_mfma_f32_16x16x32_bf16(ah[i], bl[j], acc[i][j], 0, 0, 0);
                acc[i][j] = __builtin_amdgcn_mfma_f32_16x16x32_bf16(al[i], bh[j], acc[i][j], 0, 0, 0);
            }
    }
#pragma unroll
    for (int i = 0; i < 4; i++)
#pragma unroll
        for (int j = 0; j < 4; j++) {
            const int col = n0 + nw + j * 16 + mf;
            const float bb = bias[col];
#pragma unroll
            for (int r = 0; r < 4; r++) {
                const int R = m0 + mw + i * 16 + kg * 4 + r;
                if (R < NT * NB) xih[(size_t)R * G4 + col] = acc[i][j][r] + bb;
            }
        }
}

// ---------------- phase B: persistent LSTM, fence-free coherent h exchange ----------------
// 32 blocks; block bc owns cols bc*16..+15 of each gate quadrant.
// h packed (hi<<16|lo) per element; all cross-block traffic via RELAXED agent atomics
// (per-access coherent at IF$, no acquire/release fences -> no L2 invalidation).
__global__ __launch_bounds__(256) void lstm_persistent(unsigned char* __restrict__ ws)
{
    __shared__ unsigned short Bhi[64 * 512];  // 64 KB W_hh-hi slice, XOR-swizzled 16B chunks
    const int tid = threadIdx.x;
    const int lane = tid & 63, wv = tid >> 6;
    const int mf = lane & 15, kg = lane >> 4;
    const int bc = blockIdx.x;

    unsigned int* __restrict__ hpk = (unsigned int*)(ws + OFF_HPK);
    const unsigned short* __restrict__ whh_hi = (const unsigned short*)(ws + OFF_WHH_HI);
    const unsigned short* __restrict__ whh_lo = (const unsigned short*)(ws + OFF_WHH_LO);
    const float* __restrict__ xih_base = (const float*)(ws + OFF_XIH);
    float* __restrict__ cbuf = (float*)(ws + OFF_C);
    unsigned short* __restrict__ hbuf = (unsigned short*)(ws + OFF_HBUF);
    unsigned int* __restrict__ flg = (unsigned int*)(ws + OFF_FLG);

    for (int h = 0; h < 16; ++h) {
        int s = h * 256 + tid;
        int e = s >> 6, j = s & 63;
        int q = e >> 4, ci = e & 15;
        bf16x8 v = *(const bf16x8*)(whh_hi + ((size_t)(q * 512 + bc * 16 + ci) * 512 + j * 8));
        *(bf16x8*)&Bhi[(e * 64 + (j ^ (e & 7))) * 8] = v;
    }
    __syncthreads();

    for (int t = 0; t < NT; ++t) {
        f32x4 acc[4];
#pragma unroll
        for (int q = 0; q < 4; q++) acc[q] = (f32x4){0.f, 0.f, 0.f, 0.f};

        if (t > 0) {
            const unsigned int* __restrict__ hp = hpk + ((t + 1) & 1) * (NB * NH);
            const int arow = wv * 16 + mf;
            const unsigned long long* __restrict__ prow =
                (const unsigned long long*)(hp + (size_t)arow * 512);
            for (int kk = 0; kk < 512; kk += 32) {
                const int kh = (kk + kg * 8) >> 1;  // u64 index into row
                const int jj = (kk >> 3) + kg;
                unsigned long long d0 = __hip_atomic_load(prow + kh + 0, __ATOMIC_RELAXED, __HIP_MEMORY_SCOPE_AGENT);
                unsigned long long d1 = __hip_atomic_load(prow + kh + 1, __ATOMIC_RELAXED, __HIP_MEMORY_SCOPE_AGENT);
                unsigned long long d2 = __hip_atomic_load(prow + kh + 2, __ATOMIC_RELAXED, __HIP_MEMORY_SCOPE_AGENT);
                unsigned long long d3 = __hip_atomic_load(prow + kh + 3, __ATOMIC_RELAXED, __HIP_MEMORY_SCOPE_AGENT);
                unsigned u0 = (unsigned)d0, u1 = (unsigned)(d0 >> 32);
                unsigned u2 = (unsigned)d1, u3 = (unsigned)(d1 >> 32);
                unsigned u4 = (unsigned)d2, u5 = (unsigned)(d2 >> 32);
                unsigned u6 = (unsigned)d3, u7 = (unsigned)(d3 >> 32);
                union { bf16x8 v; unsigned int u[4]; } Ahf, Alf;
                Ahf.u[0] = __builtin_amdgcn_perm(u1, u0, 0x07060302u);
                Ahf.u[1] = __builtin_amdgcn_perm(u3, u2, 0x07060302u);
                Ahf.u[2] = __builtin_amdgcn_perm(u5, u4, 0x07060302u);
                Ahf.u[3] = __builtin_amdgcn_perm(u7, u6, 0x07060302u);
                Alf.u[0] = __builtin_amdgcn_perm(u1, u0, 0x05040100u);
                Alf.u[1] = __builtin_amdgcn_perm(u3, u2, 0x05040100u);
                Alf.u[2] = __builtin_amdgcn_perm(u5, u4, 0x05040100u);
                Alf.u[3] = __builtin_amdgcn_perm(u7, u6, 0x05040100u);
#pragma unroll
                for (int q = 0; q < 4; q++) {
                    const int e = q * 16 + mf;
                    bf16x8 b_hi = *(const bf16x8*)&Bhi[(e * 64 + (jj ^ (e & 7))) * 8];
                    bf16x8 b_lo = *(const bf16x8*)(whh_lo +
                        (size_t)(q * 512 + bc * 16 + mf) * 512 + kk + kg * 8);
                    acc[q] = __builtin_amdgcn_mfma_f32_16x16x32_bf16(Ahf.v, b_hi, acc[q], 0, 0, 0);
                    acc[q] = __builtin_amdgcn_mfma_f32_16x16x32_bf16(Ahf.v, b_lo, acc[q], 0, 0, 0);
                    acc[q] = __builtin_amdgcn_mfma_f32_16x16x32_bf16(Alf.v, b_hi, acc[q], 0, 0, 0);
                }
            }
        }

        unsigned int* __restrict__ hpw = hpk + (t & 1) * (NB * NH);
        const float* __restrict__ xih = xih_base + (size_t)t * NB * G4;
        const int c = bc * 16 + mf;
#pragma unroll
        for (int r = 0; r < 4; r++) {
            const int m = wv * 16 + kg * 4 + r;
            const float gi = acc[0][r] + xih[m * G4 + 0 * 512 + c];
            const float gf = acc[1][r] + xih[m * G4 + 1 * 512 + c];
            const float gg = acc[2][r] + xih[m * G4 + 2 * 512 + c];
            const float go = acc[3][r] + xih[m * G4 + 3 * 512 + c];
            const float i_ = 1.f / (1.f + __expf(-gi));
            const float f_ = 1.f / (1.f + __expf(-gf));
            const float g_ = tanhf(gg);
            const float o_ = 1.f / (1.f + __expf(-go));
            const float c_old = (t == 0) ? 0.f : cbuf[m * NH + c];
            const float c_new = f_ * c_old + i_ * g_;
            cbuf[m * NH + c] = c_new;
            const float h_new = o_ * tanhf(c_new);
            const unsigned int hi = f2bf(h_new);
            const unsigned int lo = f2bf(h_new - bf2f((unsigned short)hi));
            __hip_atomic_store(&hpw[m * NH + c], (hi << 16) | lo,
                               __ATOMIC_RELAXED, __HIP_MEMORY_SCOPE_AGENT);
            if (t >= 1) hbuf[(t - 1) * (NB * NH) + m * NH + c] = (unsigned short)hi;
        }

        if (t < NT - 1) {
            // __syncthreads drains vmcnt (compiler-emitted) -> h stores complete
            // before our flag store. No fences anywhere: data loads are coherent.
            __syncthreads();
            if (tid < 64) {
                if (tid == 0)
                    __hip_atomic_store(&flg[t * 32 + bc], 1u,
                                       __ATOMIC_RELAXED, __HIP_MEMORY_SCOPE_AGENT);
                int done = 0;
                do {
                    unsigned v = (tid < 32)
                        ? __hip_atomic_load(&flg[t * 32 + tid],
                                            __ATOMIC_RELAXED, __HIP_MEMORY_SCOPE_AGENT)
                        : 1u;
                    done = __all(v != 0);
                    if (!done) __builtin_amdgcn_s_sleep(1);
                } while (!done);
            }
            __syncthreads();
        }
    }
}

// ---------------- phase C: Out = Hbuf[1280x512] @ W_lin^T + b_lin, tiled ----------------
__global__ __launch_bounds__(256) void gemm_c_kernel(
    unsigned char* __restrict__ ws, const float* __restrict__ b_lin, float* __restrict__ out)
{
    __shared__ unsigned short As[2][4096], Bs[2][4096];
    const int tid = threadIdx.x;
    const int lane = tid & 63, wv = tid >> 6;
    const int mf = lane & 15, kg = lane >> 4;
    const int mw = (wv >> 1) * 64, nw = (wv & 1) * 64;
    const int m0 = blockIdx.y * 128, n0 = blockIdx.x * 128;

    const unsigned short* __restrict__ hb = (const unsigned short*)(ws + OFF_HBUF);
    const unsigned short* __restrict__ wlin = (const unsigned short*)(ws + OFF_WLIN_HI);

    f32x4 acc[4][4];
#pragma unroll
    for (int i = 0; i < 4; i++)
#pragma unroll
        for (int j = 0; j < 4; j++) acc[i][j] = (f32x4){0.f, 0.f, 0.f, 0.f};

    auto stage = [&](int buf, int k0) {
#pragma unroll
        for (int h = 0; h < 2; ++h) {
            int s = h * 256 + tid;
            int r = s >> 2, ks = (s & 3) * 8;
            gl_lds16(hb + (size_t)(m0 + r) * 512 + k0 + ks, &As[buf][s * 8]);
            gl_lds16(wlin + (size_t)(n0 + r) * 512 + k0 + ks, &Bs[buf][s * 8]);
        }
    };

    stage(0, 0);
    for (int kt = 0; kt < 16; ++kt) {
        __syncthreads();
        const int cur = kt & 1;
        if (kt < 15) stage(cur ^ 1, (kt + 1) * 32);
        bf16x8 af[4], bf[4];
#pragma unroll
        for (int i = 0; i < 4; i++) {
            af[i] = *(const bf16x8*)&As[cur][(mw + i * 16 + mf) * 32 + kg * 8];
            bf[i] = *(const bf16x8*)&Bs[cur][(nw + i * 16 + mf) * 32 + kg * 8];
        }
#pragma unroll
        for (int i = 0; i < 4; i++)
#pragma unroll
            for (int j = 0; j < 4; j++)
                acc[i][j] = __builtin_amdgcn_mfma_f32_16x16x32_bf16(af[i], bf[j], acc[i][j], 0, 0, 0);
    }
#pragma unroll
    for (int i = 0; i < 4; i++)
#pragma unroll
        for (int j = 0; j < 4; j++) {
            const int col = n0 + nw + j * 16 + mf;
            if (col < NV) {
                const float bl = b_lin[col];
#pragma unroll
                for (int r = 0; r < 4; r++) {
                    const int R = m0 + mw + i * 16 + kg * 4 + r;  // = t*64 + b
                    const int b_ = R & 63, tt = R >> 6;
                    out[(size_t)b_ * ((NT - 1) * NV) + (size_t)tt * NV + col] = acc[i][j][r] + bl;
                }
            }
        }
}

extern "C" void kernel_launch(void* const* d_in, const int* in_sizes, int n_in,
                              void* d_out, int out_size, void* d_ws, size_t ws_size,
                              hipStream_t stream)
{
    const float* features = (const float*)d_in[0];
    const float* cap      = (const float*)d_in[1];
    const float* W_ih     = (const float*)d_in[2];
    const float* W_hh     = (const float*)d_in[3];
    const float* b_ih     = (const float*)d_in[4];
    const float* b_hh     = (const float*)d_in[5];
    const float* W_lin    = (const float*)d_in[6];
    const float* b_lin    = (const float*)d_in[7];
    float* out = (float*)d_out;
    unsigned char* ws = (unsigned char*)d_ws;

    // zero the barrier flags (ws is re-poisoned 0xAA before every launch)
    hipMemsetAsync(ws + OFF_FLG, 0, (NT - 1) * 32 * sizeof(unsigned int), stream);

    hipLaunchKernelGGL(prep_kernel, dim3(30888), dim3(256), 0, stream,
                       features, cap, W_ih, W_hh, b_ih, b_hh, W_lin, ws);
    hipLaunchKernelGGL(gemm_a_kernel, dim3(16, 11), dim3(256), 0, stream, ws);
    hipLaunchKernelGGL(lstm_persistent, dim3(32), dim3(256), 0, stream, ws);
    hipLaunchKernelGGL(gemm_c_kernel, dim3(79, 10), dim3(256), 0, stream, ws, b_lin, out);
}